// Round 3
// baseline (471.083 us; speedup 1.0000x reference)
//
#include <hip/hip_runtime.h>

// Integration_block: scaling-and-squaring SVF integration.
// flow = SVF * 2^-7; 7x: flow = flow + trilerp(flow, p + flow), zeros padding.
// Shape (1, 3, 160, 192, 224) fp32, planar channels in input/output.
//
// Internal layout: xyz interleaved per voxel (12 B). compose<FIRST=1> reads
// planar SVF and folds the 1/128 scale (linearity of trilerp). Each thread
// handles 2 voxels along d, with an explicit batched load phase so all 8
// row-gathers are in flight before the math (latency hiding).

#define D_ 160
#define H_ 192
#define W_ 224
static constexpr int NV = D_ * H_ * W_;   // 6,881,280 voxels
static constexpr float S_ = 0.0078125f;   // 2^-7
static constexpr int ROWS = 3 * W_;       // interleaved row stride (floats)
static constexpr int PLNS = 3 * H_ * W_;  // interleaved plane stride (floats)

template <int FIRST, int PLANAR_OUT>
__global__ __launch_bounds__(256) void compose_k(const float* __restrict__ in,
                                                 float* __restrict__ out) {
    const int w = blockIdx.x * 32 + threadIdx.x;                 // 224/32 = 7
    const int h = blockIdx.y * 4 + threadIdx.y;                  // 192/4 = 48
    const int dbase = (blockIdx.z * 2 + threadIdx.z) * 2;        // 160/(2*2) = 40

    float f0[2], f1[2], f2[2], fd[2], fh[2], fw[2];
    int idx[2], d0[2], h0[2], w0[2];
    bool inter[2];

#pragma unroll
    for (int v = 0; v < 2; ++v) {
        const int d = dbase + v;
        idx[v] = (d * H_ + h) * W_ + w;
        if (FIRST) {
            f0[v] = in[idx[v]] * S_;
            f1[v] = in[NV + idx[v]] * S_;
            f2[v] = in[2 * NV + idx[v]] * S_;
        } else {
            f0[v] = in[3 * idx[v]];
            f1[v] = in[3 * idx[v] + 1];
            f2[v] = in[3 * idx[v] + 2];
        }
        const float pd = (float)d + f0[v];
        const float ph = (float)h + f1[v];
        const float pw = (float)w + f2[v];
        const float d0f = floorf(pd), h0f = floorf(ph), w0f = floorf(pw);
        d0[v] = (int)d0f; h0[v] = (int)h0f; w0[v] = (int)w0f;
        fd[v] = pd - d0f; fh[v] = ph - h0f; fw[v] = pw - w0f;
        inter[v] = ((unsigned)d0[v] <= (unsigned)(D_ - 2)) &
                   ((unsigned)h0[v] <= (unsigned)(H_ - 2)) &
                   ((unsigned)w0[v] <= (unsigned)(W_ - 2));
    }

    float acc0[2], acc1[2], acc2[2];

    if (inter[0] & inter[1]) {
        if (FIRST) {
            // planar source: per voxel, per channel-plane, 4 rows x 2 floats
            float g0[2][4][2], g1[2][4][2], g2[2][4][2];
#pragma unroll
            for (int v = 0; v < 2; ++v) {
                const int b = (d0[v] * H_ + h0[v]) * W_ + w0[v];
                const int rb[4] = {b, b + W_, b + H_ * W_, b + H_ * W_ + W_};
#pragma unroll
                for (int r = 0; r < 4; ++r) {
                    g0[v][r][0] = in[rb[r]];
                    g0[v][r][1] = in[rb[r] + 1];
                    g1[v][r][0] = in[NV + rb[r]];
                    g1[v][r][1] = in[NV + rb[r] + 1];
                    g2[v][r][0] = in[2 * NV + rb[r]];
                    g2[v][r][1] = in[2 * NV + rb[r] + 1];
                }
            }
#pragma unroll
            for (int v = 0; v < 2; ++v) {
                const float ww1 = fw[v], ww0 = 1.f - ww1;
                const float wh1 = fh[v], wh0 = 1.f - wh1;
                const float wd1 = fd[v], wd0 = 1.f - wd1;
                const float c00 = wd0 * wh0, c01 = wd0 * wh1;
                const float c10 = wd1 * wh0, c11 = wd1 * wh1;
                acc0[v] = S_ * (c00 * (ww0 * g0[v][0][0] + ww1 * g0[v][0][1])
                              + c01 * (ww0 * g0[v][1][0] + ww1 * g0[v][1][1])
                              + c10 * (ww0 * g0[v][2][0] + ww1 * g0[v][2][1])
                              + c11 * (ww0 * g0[v][3][0] + ww1 * g0[v][3][1]));
                acc1[v] = S_ * (c00 * (ww0 * g1[v][0][0] + ww1 * g1[v][0][1])
                              + c01 * (ww0 * g1[v][1][0] + ww1 * g1[v][1][1])
                              + c10 * (ww0 * g1[v][2][0] + ww1 * g1[v][2][1])
                              + c11 * (ww0 * g1[v][3][0] + ww1 * g1[v][3][1]));
                acc2[v] = S_ * (c00 * (ww0 * g2[v][0][0] + ww1 * g2[v][0][1])
                              + c01 * (ww0 * g2[v][1][0] + ww1 * g2[v][1][1])
                              + c10 * (ww0 * g2[v][2][0] + ww1 * g2[v][2][1])
                              + c11 * (ww0 * g2[v][3][0] + ww1 * g2[v][3][1]));
            }
        } else {
            // interleaved source: per voxel 4 rows x 6 floats (both w-corners' xyz)
            float g[2][4][6];
#pragma unroll
            for (int v = 0; v < 2; ++v) {
                const int base = (d0[v] * H_ + h0[v]) * ROWS + w0[v] * 3;
                const float* r0 = in + base;
                const float* r1 = in + base + ROWS;
                const float* r2 = in + base + PLNS;
                const float* r3 = in + base + PLNS + ROWS;
#pragma unroll
                for (int j = 0; j < 6; ++j) g[v][0][j] = r0[j];
#pragma unroll
                for (int j = 0; j < 6; ++j) g[v][1][j] = r1[j];
#pragma unroll
                for (int j = 0; j < 6; ++j) g[v][2][j] = r2[j];
#pragma unroll
                for (int j = 0; j < 6; ++j) g[v][3][j] = r3[j];
            }
#pragma unroll
            for (int v = 0; v < 2; ++v) {
                const float ww1 = fw[v], ww0 = 1.f - ww1;
                const float wh1 = fh[v], wh0 = 1.f - wh1;
                const float wd1 = fd[v], wd0 = 1.f - wd1;
                const float c00 = wd0 * wh0, c01 = wd0 * wh1;
                const float c10 = wd1 * wh0, c11 = wd1 * wh1;
                acc0[v] = c00 * (ww0 * g[v][0][0] + ww1 * g[v][0][3])
                        + c01 * (ww0 * g[v][1][0] + ww1 * g[v][1][3])
                        + c10 * (ww0 * g[v][2][0] + ww1 * g[v][2][3])
                        + c11 * (ww0 * g[v][3][0] + ww1 * g[v][3][3]);
                acc1[v] = c00 * (ww0 * g[v][0][1] + ww1 * g[v][0][4])
                        + c01 * (ww0 * g[v][1][1] + ww1 * g[v][1][4])
                        + c10 * (ww0 * g[v][2][1] + ww1 * g[v][2][4])
                        + c11 * (ww0 * g[v][3][1] + ww1 * g[v][3][4]);
                acc2[v] = c00 * (ww0 * g[v][0][2] + ww1 * g[v][0][5])
                        + c01 * (ww0 * g[v][1][2] + ww1 * g[v][1][5])
                        + c10 * (ww0 * g[v][2][2] + ww1 * g[v][2][5])
                        + c11 * (ww0 * g[v][3][2] + ww1 * g[v][3][5]);
            }
        }
    } else {
        // boundary fallback: per-voxel, per-corner bounds checks
#pragma unroll
        for (int v = 0; v < 2; ++v) {
            float a0 = 0.f, a1 = 0.f, a2 = 0.f;
#pragma unroll
            for (int dz = 0; dz < 2; ++dz) {
                const int cd = d0[v] + dz;
                if ((unsigned)cd >= (unsigned)D_) continue;
                const float wz = dz ? fd[v] : (1.f - fd[v]);
#pragma unroll
                for (int dy = 0; dy < 2; ++dy) {
                    const int ch = h0[v] + dy;
                    if ((unsigned)ch >= (unsigned)H_) continue;
                    const float wzy = wz * (dy ? fh[v] : (1.f - fh[v]));
                    const int rowbase = (cd * H_ + ch) * W_;
#pragma unroll
                    for (int dx = 0; dx < 2; ++dx) {
                        const int cw = w0[v] + dx;
                        if ((unsigned)cw >= (unsigned)W_) continue;
                        const float wt = wzy * (dx ? fw[v] : (1.f - fw[v]));
                        if (FIRST) {
                            const int j = rowbase + cw;
                            a0 += wt * in[j];
                            a1 += wt * in[NV + j];
                            a2 += wt * in[2 * NV + j];
                        } else {
                            const int j = (rowbase + cw) * 3;
                            a0 += wt * in[j];
                            a1 += wt * in[j + 1];
                            a2 += wt * in[j + 2];
                        }
                    }
                }
            }
            if (FIRST) { a0 *= S_; a1 *= S_; a2 *= S_; }
            acc0[v] = a0; acc1[v] = a1; acc2[v] = a2;
        }
    }

#pragma unroll
    for (int v = 0; v < 2; ++v) {
        const float o0 = f0[v] + acc0[v];
        const float o1 = f1[v] + acc1[v];
        const float o2 = f2[v] + acc2[v];
        if (PLANAR_OUT) {
            out[idx[v]]          = o0;
            out[NV + idx[v]]     = o1;
            out[2 * NV + idx[v]] = o2;
        } else {
            out[3 * idx[v]]     = o0;
            out[3 * idx[v] + 1] = o1;
            out[3 * idx[v] + 2] = o2;
        }
    }
}

extern "C" void kernel_launch(void* const* d_in, const int* in_sizes, int n_in,
                              void* d_out, int out_size, void* d_ws, size_t ws_size,
                              hipStream_t stream) {
    const float* svf = (const float*)d_in[0];
    float* outp = (float*)d_out;   // doubles as interleaved scratch until final pass
    float* wsA  = (float*)d_ws;

    dim3 blk(32, 4, 2);
    dim3 grd(W_ / 32, H_ / 4, D_ / 4);   // (7, 48, 40)

    // c0: svf(planar) -> out (interleaved), scale folded in
    compose_k<1, 0><<<grd, blk, 0, stream>>>(svf, outp);
    // c1..c5 ping-pong interleaved
    compose_k<0, 0><<<grd, blk, 0, stream>>>(outp, wsA);
    compose_k<0, 0><<<grd, blk, 0, stream>>>(wsA, outp);
    compose_k<0, 0><<<grd, blk, 0, stream>>>(outp, wsA);
    compose_k<0, 0><<<grd, blk, 0, stream>>>(wsA, outp);
    compose_k<0, 0><<<grd, blk, 0, stream>>>(outp, wsA);
    // c6: -> planar into d_out
    compose_k<0, 1><<<grd, blk, 0, stream>>>(wsA, outp);
}

// Round 4
// 423.996 us; speedup vs baseline: 1.1111x; 1.1111x over previous
//
#include <hip/hip_runtime.h>

// Integration_block: scaling-and-squaring SVF integration.
// flow = SVF * 2^-7; 7x: flow = flow + trilerp(flow, p + flow), zeros padding.
// Shape (1, 3, 160, 192, 224) fp32, planar channels in input/output.
//
// Internal layout: xyz interleaved (12 B/voxel) so the 8-corner gather is
// 4 contiguous 24 B row-loads (dwordx4+dwordx2 each). A sched_barrier(0)
// between the load cluster and the math forces all 8 gather loads in flight
// behind ONE waitcnt (2 memory rounds per wave instead of ~3-4).

#define D_ 160
#define H_ 192
#define W_ 224
static constexpr int NV = D_ * H_ * W_;   // 6,881,280
static constexpr float S_ = 0.0078125f;   // 2^-7
static constexpr int ROWS = 3 * W_;       // interleaved row stride (floats)
static constexpr int PLNS = 3 * H_ * W_;  // interleaved plane stride (floats)

// 24B row-pair: both w-corners' xyz. align(4): base is only dword-aligned.
struct __attribute__((packed, aligned(4))) Row6 { float v[6]; };

__global__ __launch_bounds__(256) void scale_k(const float* __restrict__ svf,
                                               float* __restrict__ out) {
    int i = blockIdx.x * 256 + threadIdx.x;        // 4-voxel group; NV/4 groups
    float4 a = ((const float4*)svf)[i];
    float4 b = ((const float4*)(svf + NV))[i];
    float4 c = ((const float4*)(svf + 2 * NV))[i];
    a.x *= S_; a.y *= S_; a.z *= S_; a.w *= S_;
    b.x *= S_; b.y *= S_; b.z *= S_; b.w *= S_;
    c.x *= S_; c.y *= S_; c.z *= S_; c.w *= S_;
    float4* o = (float4*)out + 3 * i;
    o[0] = make_float4(a.x, b.x, c.x, a.y);
    o[1] = make_float4(b.y, c.y, a.z, b.z);
    o[2] = make_float4(c.z, a.w, b.w, c.w);
}

template <int PLANAR_OUT>
__global__ __launch_bounds__(256) void compose_k(const float* __restrict__ in,
                                                 float* __restrict__ out) {
    const int w = blockIdx.x * 32 + threadIdx.x;   // 224/32 = 7
    const int h = blockIdx.y * 4 + threadIdx.y;    // 192/4  = 48
    const int d = blockIdx.z * 2 + threadIdx.z;    // 160/2  = 80
    const int idx = (d * H_ + h) * W_ + w;

    const float f0 = in[3 * idx];
    const float f1 = in[3 * idx + 1];
    const float f2 = in[3 * idx + 2];

    const float pd = (float)d + f0;
    const float ph = (float)h + f1;
    const float pw = (float)w + f2;
    const float d0f = floorf(pd), h0f = floorf(ph), w0f = floorf(pw);
    const int d0 = (int)d0f, h0 = (int)h0f, w0 = (int)w0f;
    const float fd = pd - d0f, fh = ph - h0f, fw = pw - w0f;

    float acc0, acc1, acc2;

    const bool interior = ((unsigned)d0 <= (unsigned)(D_ - 2)) &
                          ((unsigned)h0 <= (unsigned)(H_ - 2)) &
                          ((unsigned)w0 <= (unsigned)(W_ - 2));

    if (interior) {
        const int base = (d0 * H_ + h0) * ROWS + 3 * w0;
        // All 8 gather loads issued before any consumer (one vmcnt round).
        Row6 r00 = *(const Row6*)(in + base);               // (d0,   h0  )
        Row6 r01 = *(const Row6*)(in + base + ROWS);        // (d0,   h0+1)
        Row6 r10 = *(const Row6*)(in + base + PLNS);        // (d0+1, h0  )
        Row6 r11 = *(const Row6*)(in + base + PLNS + ROWS); // (d0+1, h0+1)
        __builtin_amdgcn_sched_barrier(0);

        const float ww1 = fw, ww0 = 1.f - fw;
        const float wh1 = fh, wh0 = 1.f - fh;
        const float wd1 = fd, wd0 = 1.f - fd;
        const float c00 = wd0 * wh0, c01 = wd0 * wh1;
        const float c10 = wd1 * wh0, c11 = wd1 * wh1;

        acc0 = c00 * (ww0 * r00.v[0] + ww1 * r00.v[3])
             + c01 * (ww0 * r01.v[0] + ww1 * r01.v[3])
             + c10 * (ww0 * r10.v[0] + ww1 * r10.v[3])
             + c11 * (ww0 * r11.v[0] + ww1 * r11.v[3]);
        acc1 = c00 * (ww0 * r00.v[1] + ww1 * r00.v[4])
             + c01 * (ww0 * r01.v[1] + ww1 * r01.v[4])
             + c10 * (ww0 * r10.v[1] + ww1 * r10.v[4])
             + c11 * (ww0 * r11.v[1] + ww1 * r11.v[4]);
        acc2 = c00 * (ww0 * r00.v[2] + ww1 * r00.v[5])
             + c01 * (ww0 * r01.v[2] + ww1 * r01.v[5])
             + c10 * (ww0 * r10.v[2] + ww1 * r10.v[5])
             + c11 * (ww0 * r11.v[2] + ww1 * r11.v[5]);
    } else {
        acc0 = acc1 = acc2 = 0.f;
#pragma unroll
        for (int dz = 0; dz < 2; ++dz) {
            const int cd = d0 + dz;
            if ((unsigned)cd >= (unsigned)D_) continue;
            const float wz = dz ? fd : (1.f - fd);
#pragma unroll
            for (int dy = 0; dy < 2; ++dy) {
                const int ch = h0 + dy;
                if ((unsigned)ch >= (unsigned)H_) continue;
                const float wzy = wz * (dy ? fh : (1.f - fh));
                const int rowbase = (cd * H_ + ch) * W_;
#pragma unroll
                for (int dx = 0; dx < 2; ++dx) {
                    const int cw = w0 + dx;
                    if ((unsigned)cw >= (unsigned)W_) continue;
                    const float wt = wzy * (dx ? fw : (1.f - fw));
                    const int j = (rowbase + cw) * 3;
                    acc0 += wt * in[j];
                    acc1 += wt * in[j + 1];
                    acc2 += wt * in[j + 2];
                }
            }
        }
    }

    const float o0 = f0 + acc0;
    const float o1 = f1 + acc1;
    const float o2 = f2 + acc2;
    if (PLANAR_OUT) {
        out[idx]          = o0;
        out[NV + idx]     = o1;
        out[2 * NV + idx] = o2;
    } else {
        out[3 * idx]     = o0;
        out[3 * idx + 1] = o1;
        out[3 * idx + 2] = o2;
    }
}

extern "C" void kernel_launch(void* const* d_in, const int* in_sizes, int n_in,
                              void* d_out, int out_size, void* d_ws, size_t ws_size,
                              hipStream_t stream) {
    const float* svf = (const float*)d_in[0];
    float* outp = (float*)d_out;   // doubles as interleaved scratch until final pass
    float* wsA  = (float*)d_ws;

    scale_k<<<NV / 4 / 256, 256, 0, stream>>>(svf, wsA);

    dim3 blk(32, 4, 2);
    dim3 grd(W_ / 32, H_ / 4, D_ / 2);   // (7, 48, 80)

    // c0: wsA->out, ping-pong, c6 -> planar into d_out (7 odd => ends in d_out)
    const float* cur = wsA;
    float* nxt = outp;
    for (int it = 0; it < 6; ++it) {
        compose_k<0><<<grd, blk, 0, stream>>>(cur, nxt);
        const float* tmp = nxt;
        nxt = (float*)cur;
        cur = tmp;
    }
    compose_k<1><<<grd, blk, 0, stream>>>(cur, outp);
}